// Round 8
// baseline (361.672 us; speedup 1.0000x reference)
//
#include <hip/hip_runtime.h>
#include <hip/hip_bf16.h>

// Problem: B=4, N=512, RBF=32, F=16
// image   (B,N,N,32) f32   d_in[0]
// vectors (B,N,N,3)  f32   d_in[1]
// feat0   (B,N,16,1) f32   d_in[2]
// feat1   (B,N,16,3) f32   d_in[3]
// W00,b00,W01,b01,W10,b10,W11,b11  d_in[4..11]
// out: out1(B,N,16,1) | out2(B,N,16,3) | out3(B,N,16,3) | out4(B,N,16,1) | out5(B,N,16,3)
//
// Round 8 (= round 7 resubmitted; GPU acquisition timed out, kernel untested):
// 2-phase LDS pipeline. Per wave, per 16-b tile: image/feat0/feat1 staged via
// global_load_lds (zero VGPR cost) into a private 6144B buffer, double-
// buffered. Loop: waitcnt(stage cur) -> ds_read cur -> stage next -> compute.
// No intra-loop barriers (buffers are wave-private). Image staged with
// pre-swizzled global source (16B-chunk XOR s^(r&7)) so A-frag ds_read_b128
// is conflict-free. vectors stay direct float4 (L2-hot). LDS 48KB+3KB ->
// 3 blocks/CU; launch_bounds(256,3) so no reg-cap spill (r3/r4/r5 lesson:
// register banking spills; LDS banking is free).

typedef __attribute__((ext_vector_type(8))) short short8;
typedef __attribute__((ext_vector_type(4))) float f32x4;

#define EPS2 1e-14f

static __device__ __forceinline__ short f2bf(float x) {
    __hip_bfloat16 h = __float2bfloat16(x);
    return *reinterpret_cast<short*>(&h);
}

static __device__ __forceinline__ void gload16(const void* g, void* l) {
    __builtin_amdgcn_global_load_lds(
        (const __attribute__((address_space(1))) void*)g,
        (__attribute__((address_space(3))) void*)l,
        16, 0, 0);
}

__global__ __launch_bounds__(256, 3) void conv_mfma_ldspipe_kernel(
    const float* __restrict__ image,
    const float* __restrict__ vectors,
    const float* __restrict__ feat0,
    const float* __restrict__ feat1,
    const float* __restrict__ W00, const float* __restrict__ b00,
    const float* __restrict__ W01, const float* __restrict__ b01,
    const float* __restrict__ W10, const float* __restrict__ b10,
    const float* __restrict__ W11, const float* __restrict__ b11,
    float* __restrict__ out)
{
    // per-wave double buffer: [wave][buf] of 6144B = img 2048 | f0 1024 | f1 3072
    __shared__ __align__(16) char smem[4 * 2 * 6144];
    __shared__ float red[4][16][12];     // [wave][f][comp(11 pad 12)]

    const int t    = threadIdx.x;
    const int wave = t >> 6;
    const int lane = t & 63;
    const int f    = lane & 15;          // B col / D col
    const int g    = lane >> 4;          // k-group (A/B), row-group (D)
    const int ma   = blockIdx.x;         // m*512 + a
    const int m    = ma >> 9;

    // ---- weight fragments (VGPR-resident, once per block) ----
    short8 wf0, wf1, wf2, wf3;
    float bias0, bias1, bias2, bias3;
    {
        #pragma unroll
        for (int j = 0; j < 8; ++j) {
            const int k = g * 8 + j;
            wf0[j] = f2bf(W00[k * 16 + f]);
            wf1[j] = f2bf(W01[k * 16 + f]);
            wf2[j] = f2bf(W10[k * 16 + f]);
            wf3[j] = f2bf(W11[k * 16 + f]);
        }
        bias0 = b00[f]; bias1 = b01[f]; bias2 = b10[f]; bias3 = b11[f];
    }

    const float* imgbase = image   + (size_t)ma * (512 * 32);
    const float* vecbase = vectors + (size_t)ma * (512 * 3);
    const float* f0base  = feat0   + (size_t)m  * (512 * 16);
    const float* f1base  = feat1   + (size_t)m  * (512 * 16 * 3);

    float acc1 = 0.f, acc4 = 0.f;
    float acc2x = 0.f, acc2y = 0.f, acc2z = 0.f;
    float acc3x = 0.f, acc3y = 0.f, acc3z = 0.f;
    float acc5x = 0.f, acc5y = 0.f, acc5z = 0.f;

    const int bbase = wave * 128;            // wave's b range: [bbase, bbase+128)
    const unsigned wlds = (unsigned)wave * 12288u;

    // stage tile TT into LDS byte offset DST (wave-uniform):
    //  img: 2048B, 16B chunks; LDS slot (r,s) gets global chunk (r, s^(r&7))
    //  f0:  1024B linear;  f1: 3072B linear
#define STAGE(TT, DST) { \
    const char* imgT_ = (const char*)(imgbase + (size_t)(bbase + (TT) * 16) * 32); \
    const char* f0T_  = (const char*)(f0base + (bbase + (TT) * 16) * 16); \
    const char* f1T_  = (const char*)(f1base + (size_t)(bbase + (TT) * 16) * 48); \
    { const int i_ = lane;      const int r_ = i_ >> 3, s_ = i_ & 7; \
      gload16(imgT_ + (((r_ << 3) + (s_ ^ (r_ & 7))) << 4), smem + (DST)); } \
    { const int i_ = lane + 64; const int r_ = i_ >> 3, s_ = i_ & 7; \
      gload16(imgT_ + (((r_ << 3) + (s_ ^ (r_ & 7))) << 4), smem + (DST) + 1024); } \
    gload16(f0T_ + (lane << 4),        smem + (DST) + 2048); \
    gload16(f1T_ + (lane << 4),        smem + (DST) + 3072); \
    gload16(f1T_ + (lane << 4) + 1024, smem + (DST) + 4096); \
    gload16(f1T_ + (lane << 4) + 2048, smem + (DST) + 5120); \
}

#define TAIL(R00, R01, R10, R11, VX, VY, VZ, F0V, U0, U1, U2) { \
    const float vx_ = (VX), vy_ = (VY), vz_ = (VZ); \
    const float n2_ = vx_ * vx_ + vy_ * vy_ + vz_ * vz_; \
    const bool keep_ = n2_ >= EPS2; \
    const float r00_ = (R00); \
    const float r01_ = keep_ ? (R01) : 0.f; \
    const float r10_ = (R10); \
    const float r11_ = keep_ ? (R11) : 0.f; \
    const float f0v_ = (F0V); \
    const float u0_ = (U0), u1_ = (U1), u2_ = (U2); \
    acc1 = fmaf(r00_, f0v_, acc1); \
    const float t01_ = r01_ * f0v_; \
    acc2x = fmaf(t01_, vx_, acc2x); \
    acc2y = fmaf(t01_, vy_, acc2y); \
    acc2z = fmaf(t01_, vz_, acc2z); \
    acc3x = fmaf(r10_, u0_, acc3x); \
    acc3y = fmaf(r10_, u1_, acc3y); \
    acc3z = fmaf(r10_, u2_, acc3z); \
    const float dd_ = fmaf(vx_, u0_, fmaf(vy_, u1_, vz_ * u2_)); \
    acc4 = fmaf(r11_, dd_, acc4); \
    acc5x = fmaf(r11_, vy_ * u2_ - vz_ * u1_, acc5x); \
    acc5y = fmaf(r11_, vz_ * u0_ - vx_ * u2_, acc5y); \
    acc5z = fmaf(r11_, vx_ * u1_ - vy_ * u0_, acc5z); \
}

    // prologue: stage tile 0 into buf 0
    STAGE(0, wlds)

    #pragma unroll
    for (int tt = 0; tt < 8; ++tt) {
        const int cur = tt & 1;

        // wait for stage(cur) [issued one tile ago]; nothing newer outstanding
        asm volatile("s_waitcnt vmcnt(0)" ::: "memory");
        __builtin_amdgcn_sched_barrier(0);

        // ---- ds_reads from buf cur ----
        const char* cb = smem + wlds + (unsigned)cur * 6144u;
        const float4 a0 = *(const float4*)(cb + f * 128 + (((2 * g)     ^ (f & 7)) << 4));
        const float4 a1 = *(const float4*)(cb + f * 128 + (((2 * g + 1) ^ (f & 7)) << 4));
        const float* f0s = (const float*)(cb + 2048);
        const float F0a = f0s[(4 * g + 0) * 16 + f];
        const float F0b = f0s[(4 * g + 1) * 16 + f];
        const float F0c = f0s[(4 * g + 2) * 16 + f];
        const float F0d = f0s[(4 * g + 3) * 16 + f];
        const float* f1s = (const float*)(cb + 3072);
        const float U00 = f1s[(4 * g + 0) * 48 + f * 3 + 0];
        const float U01 = f1s[(4 * g + 0) * 48 + f * 3 + 1];
        const float U02 = f1s[(4 * g + 0) * 48 + f * 3 + 2];
        const float U10 = f1s[(4 * g + 1) * 48 + f * 3 + 0];
        const float U11 = f1s[(4 * g + 1) * 48 + f * 3 + 1];
        const float U12 = f1s[(4 * g + 1) * 48 + f * 3 + 2];
        const float U20 = f1s[(4 * g + 2) * 48 + f * 3 + 0];
        const float U21 = f1s[(4 * g + 2) * 48 + f * 3 + 1];
        const float U22 = f1s[(4 * g + 2) * 48 + f * 3 + 2];
        const float U30 = f1s[(4 * g + 3) * 48 + f * 3 + 0];
        const float U31 = f1s[(4 * g + 3) * 48 + f * 3 + 1];
        const float U32 = f1s[(4 * g + 3) * 48 + f * 3 + 2];

        // vectors: direct global (L2-hot, 48B-aligned)
        const int bb = bbase + tt * 16 + 4 * g;
        const float* vp = vecbase + bb * 3;
        const float4 V0 = *(const float4*)(vp);
        const float4 V1 = *(const float4*)(vp + 4);
        const float4 V2 = *(const float4*)(vp + 8);

        __builtin_amdgcn_sched_barrier(0);
        // ---- stage next tile into the other buffer ----
        if (tt < 7) { STAGE(tt + 1, wlds + (unsigned)(cur ^ 1) * 6144u) }
        __builtin_amdgcn_sched_barrier(0);

        // ---- compute ----
        short8 af;
        af[0] = f2bf(a0.x); af[1] = f2bf(a0.y);
        af[2] = f2bf(a0.z); af[3] = f2bf(a0.w);
        af[4] = f2bf(a1.x); af[5] = f2bf(a1.y);
        af[6] = f2bf(a1.z); af[7] = f2bf(a1.w);

        f32x4 d0 = {bias0, bias0, bias0, bias0};
        f32x4 d1 = {bias1, bias1, bias1, bias1};
        f32x4 d2 = {bias2, bias2, bias2, bias2};
        f32x4 d3 = {bias3, bias3, bias3, bias3};
        d0 = __builtin_amdgcn_mfma_f32_16x16x32_bf16(af, wf0, d0, 0, 0, 0);
        d1 = __builtin_amdgcn_mfma_f32_16x16x32_bf16(af, wf1, d1, 0, 0, 0);
        d2 = __builtin_amdgcn_mfma_f32_16x16x32_bf16(af, wf2, d2, 0, 0, 0);
        d3 = __builtin_amdgcn_mfma_f32_16x16x32_bf16(af, wf3, d3, 0, 0, 0);

        TAIL(d0[0], d1[0], d2[0], d3[0], V0.x, V0.y, V0.z, F0a, U00, U01, U02)
        TAIL(d0[1], d1[1], d2[1], d3[1], V0.w, V1.x, V1.y, F0b, U10, U11, U12)
        TAIL(d0[2], d1[2], d2[2], d3[2], V1.z, V1.w, V2.x, F0c, U20, U21, U22)
        TAIL(d0[3], d1[3], d2[3], d3[3], V2.y, V2.z, V2.w, F0d, U30, U31, U32)
    }
#undef TAIL
#undef STAGE

    // ---- in-wave reduce over the 4 lane-groups sharing f ----
    #define WRED(x) x += __shfl_xor(x, 16); x += __shfl_xor(x, 32);
    WRED(acc1)  WRED(acc2x) WRED(acc2y) WRED(acc2z)
    WRED(acc3x) WRED(acc3y) WRED(acc3z) WRED(acc4)
    WRED(acc5x) WRED(acc5y) WRED(acc5z)
    #undef WRED

    if (lane < 16) {
        red[wave][f][0]  = acc1;
        red[wave][f][1]  = acc2x;
        red[wave][f][2]  = acc2y;
        red[wave][f][3]  = acc2z;
        red[wave][f][4]  = acc3x;
        red[wave][f][5]  = acc3y;
        red[wave][f][6]  = acc3z;
        red[wave][f][7]  = acc4;
        red[wave][f][8]  = acc5x;
        red[wave][f][9]  = acc5y;
        red[wave][f][10] = acc5z;
    }
    __syncthreads();

    if (t < 176) {
        const int ff = t / 11;
        const int comp = t % 11;
        float s = red[0][ff][comp] + red[1][ff][comp]
                + red[2][ff][comp] + red[3][ff][comp];

        const size_t base16 = (size_t)ma * 16 + ff;
        const size_t base48 = base16 * 3;
        if (comp == 0)      out[base16] = s;
        else if (comp < 4)  out[32768  + base48 + (comp - 1)] = s;
        else if (comp < 7)  out[131072 + base48 + (comp - 4)] = s;
        else if (comp == 7) out[229376 + base16] = s;
        else                out[262144 + base48 + (comp - 8)] = s;
    }
}

extern "C" void kernel_launch(void* const* d_in, const int* in_sizes, int n_in,
                              void* d_out, int out_size, void* d_ws, size_t ws_size,
                              hipStream_t stream) {
    const float* image   = (const float*)d_in[0];
    const float* vectors = (const float*)d_in[1];
    const float* feat0   = (const float*)d_in[2];
    const float* feat1   = (const float*)d_in[3];
    const float* W00 = (const float*)d_in[4];
    const float* b00 = (const float*)d_in[5];
    const float* W01 = (const float*)d_in[6];
    const float* b01 = (const float*)d_in[7];
    const float* W10 = (const float*)d_in[8];
    const float* b10 = (const float*)d_in[9];
    const float* W11 = (const float*)d_in[10];
    const float* b11 = (const float*)d_in[11];
    float* out = (float*)d_out;

    conv_mfma_ldspipe_kernel<<<4 * 512, 256, 0, stream>>>(
        image, vectors, feat0, feat1,
        W00, b00, W01, b01, W10, b10, W11, b11, out);
}

// Round 9
// 270.003 us; speedup vs baseline: 1.3395x; 1.3395x over previous
//
#include <hip/hip_runtime.h>
#include <hip/hip_bf16.h>

// Problem: B=4, N=512, RBF=32, F=16
// image   (B,N,N,32) f32   d_in[0]
// vectors (B,N,N,3)  f32   d_in[1]
// feat0   (B,N,16,1) f32   d_in[2]
// feat1   (B,N,16,3) f32   d_in[3]
// W00,b00,W01,b01,W10,b10,W11,b11  d_in[4..11]
// out: out1(B,N,16,1) | out2(B,N,16,3) | out3(B,N,16,3) | out4(B,N,16,1) | out5(B,N,16,3)
//
// Round 9: compiler-native LDS double-buffer (m97 pattern). global_load_lds +
// __syncthreads only — NO inline-asm fences (r8's fences forced liveness ->
// scratch). Per tile: barrier (drains stage t) -> issue stage t+1 -> ds_read t
// -> compute t. Image staged with pre-swizzled source (XOR s^(r&7)): A-frag
// b128 reads 2-way (free). Row permutation sigma(r)=4(r&3)+(r>>2) on A-rows
// makes each lane own b's {4*reg+g} so f0/f1 reads across g-groups hit banks
// +16 apart (2-way, free) instead of 4-way. f1 via ds_read_b96 (float3).

typedef __attribute__((ext_vector_type(8))) short short8;
typedef __attribute__((ext_vector_type(4))) float f32x4;

#define EPS2 1e-14f

static __device__ __forceinline__ short f2bf(float x) {
    __hip_bfloat16 h = __float2bfloat16(x);
    return *reinterpret_cast<short*>(&h);
}

static __device__ __forceinline__ void gload16(const void* g, void* l) {
    __builtin_amdgcn_global_load_lds(
        (const __attribute__((address_space(1))) void*)g,
        (__attribute__((address_space(3))) void*)l,
        16, 0, 0);
}

__global__ __launch_bounds__(256, 4) void conv_mfma_coop_kernel(
    const float* __restrict__ image,
    const float* __restrict__ vectors,
    const float* __restrict__ feat0,
    const float* __restrict__ feat1,
    const float* __restrict__ W00, const float* __restrict__ b00,
    const float* __restrict__ W01, const float* __restrict__ b01,
    const float* __restrict__ W10, const float* __restrict__ b10,
    const float* __restrict__ W11, const float* __restrict__ b11,
    float* __restrict__ out)
{
    // per-wave double buffer: [wave][buf] of 6144B = img 2048 | f0 1024 | f1 3072
    __shared__ __align__(16) char smem[4 * 2 * 6144];
    __shared__ float red[4][16][12];     // [wave][f][comp(11 pad 12)]

    const int t    = threadIdx.x;
    const int wave = t >> 6;
    const int lane = t & 63;
    const int f    = lane & 15;          // B col / D col
    const int g    = lane >> 4;          // k-group (A/B), row-group (D)
    const int ma   = blockIdx.x;         // m*512 + a
    const int m    = ma >> 9;

    // ---- weight fragments (VGPR-resident, once per block) ----
    short8 wf0, wf1, wf2, wf3;
    float bias0, bias1, bias2, bias3;
    {
        #pragma unroll
        for (int j = 0; j < 8; ++j) {
            const int k = g * 8 + j;
            wf0[j] = f2bf(W00[k * 16 + f]);
            wf1[j] = f2bf(W01[k * 16 + f]);
            wf2[j] = f2bf(W10[k * 16 + f]);
            wf3[j] = f2bf(W11[k * 16 + f]);
        }
        bias0 = b00[f]; bias1 = b01[f]; bias2 = b10[f]; bias3 = b11[f];
    }

    const float* imgbase = image   + (size_t)ma * (512 * 32);
    const float* vecbase = vectors + (size_t)ma * (512 * 3);
    const float* f0base  = feat0   + (size_t)m  * (512 * 16);
    const float* f1base  = feat1   + (size_t)m  * (512 * 16 * 3);

    float acc1 = 0.f, acc4 = 0.f;
    float acc2x = 0.f, acc2y = 0.f, acc2z = 0.f;
    float acc3x = 0.f, acc3y = 0.f, acc3z = 0.f;
    float acc5x = 0.f, acc5y = 0.f, acc5z = 0.f;

    const int bbase = wave * 128;        // wave's b range: [bbase, bbase+128)
    const unsigned wlds = (unsigned)wave * 12288u;

    // image staging source offsets (sigma row permutation + XOR chunk swizzle)
    // LDS slot (r, s) <- global row sigma(r), chunk s^(r&7); slot idx = lane (+64)
    const int r0 = lane >> 3, s0 = lane & 7;
    const int sr0 = ((r0 & 3) << 2) + (r0 >> 2);
    const int isrc0 = sr0 * 128 + ((s0 ^ (r0 & 7)) << 4);
    const int r1 = r0 + 8;
    const int sr1 = ((r1 & 3) << 2) + (r1 >> 2);
    const int isrc1 = sr1 * 128 + ((s0 ^ (r1 & 7)) << 4);

#define STAGE(TT, BUF) { \
    const char* imgT_ = (const char*)(imgbase + (size_t)(bbase + (TT) * 16) * 32); \
    const char* f0T_  = (const char*)(f0base + (bbase + (TT) * 16) * 16); \
    const char* f1T_  = (const char*)(f1base + (size_t)(bbase + (TT) * 16) * 48); \
    char* db_ = smem + wlds + (BUF) * 6144; \
    gload16(imgT_ + isrc0, db_); \
    gload16(imgT_ + isrc1, db_ + 1024); \
    gload16(f0T_ + (lane << 4), db_ + 2048); \
    gload16(f1T_ + (lane << 4), db_ + 3072); \
    gload16(f1T_ + (lane << 4) + 1024, db_ + 4096); \
    gload16(f1T_ + (lane << 4) + 2048, db_ + 5120); \
}

#define TAIL(R00, R01, R10, R11, VX, VY, VZ, F0V, U0, U1, U2) { \
    const float vx_ = (VX), vy_ = (VY), vz_ = (VZ); \
    const float n2_ = vx_ * vx_ + vy_ * vy_ + vz_ * vz_; \
    const bool keep_ = n2_ >= EPS2; \
    const float r00_ = (R00); \
    const float r01_ = keep_ ? (R01) : 0.f; \
    const float r10_ = (R10); \
    const float r11_ = keep_ ? (R11) : 0.f; \
    const float f0v_ = (F0V); \
    const float u0_ = (U0), u1_ = (U1), u2_ = (U2); \
    acc1 = fmaf(r00_, f0v_, acc1); \
    const float t01_ = r01_ * f0v_; \
    acc2x = fmaf(t01_, vx_, acc2x); \
    acc2y = fmaf(t01_, vy_, acc2y); \
    acc2z = fmaf(t01_, vz_, acc2z); \
    acc3x = fmaf(r10_, u0_, acc3x); \
    acc3y = fmaf(r10_, u1_, acc3y); \
    acc3z = fmaf(r10_, u2_, acc3z); \
    const float dd_ = fmaf(vx_, u0_, fmaf(vy_, u1_, vz_ * u2_)); \
    acc4 = fmaf(r11_, dd_, acc4); \
    acc5x = fmaf(r11_, vy_ * u2_ - vz_ * u1_, acc5x); \
    acc5y = fmaf(r11_, vz_ * u0_ - vx_ * u2_, acc5y); \
    acc5z = fmaf(r11_, vx_ * u1_ - vy_ * u0_, acc5z); \
}

    // prologue: stage tile 0 into buf 0
    STAGE(0, 0)

    #pragma unroll
    for (int tt = 0; tt < 8; ++tt) {
        __syncthreads();                 // drains stage(tt) (compiler-inserted vmcnt)

        if (tt < 7) { STAGE(tt + 1, (tt + 1) & 1) }   // in flight under compute(tt)

        const char* cb = smem + wlds + (unsigned)(tt & 1) * 6144u;

        // A fragment: slot row f, chunks (2g)^ (f&7), (2g+1)^(f&7)  [2-way free]
        const float4 a0 = *(const float4*)(cb + f * 128 + (((2 * g)     ^ (f & 7)) << 4));
        const float4 a1 = *(const float4*)(cb + f * 128 + (((2 * g + 1) ^ (f & 7)) << 4));

        // lane owns b = b0 + 4*reg + g (sigma remap) -> g-groups 16 banks apart
        const float* f0s = (const float*)(cb + 2048);
        const float F0a = f0s[(g     ) * 16 + f];
        const float F0b = f0s[(g +  4) * 16 + f];
        const float F0c = f0s[(g +  8) * 16 + f];
        const float F0d = f0s[(g + 12) * 16 + f];
        const float* f1s = (const float*)(cb + 3072);
        const float3 U_0 = *(const float3*)(f1s + (g     ) * 48 + f * 3);
        const float3 U_1 = *(const float3*)(f1s + (g +  4) * 48 + f * 3);
        const float3 U_2 = *(const float3*)(f1s + (g +  8) * 48 + f * 3);
        const float3 U_3 = *(const float3*)(f1s + (g + 12) * 48 + f * 3);

        // vectors: direct global (L2-hot); b's strided by 4
        const float* vp = vecbase + (bbase + tt * 16 + g) * 3;
        const float3 V_0 = *(const float3*)(vp);
        const float3 V_1 = *(const float3*)(vp + 12);
        const float3 V_2 = *(const float3*)(vp + 24);
        const float3 V_3 = *(const float3*)(vp + 36);

        // ---- compute ----
        short8 af;
        af[0] = f2bf(a0.x); af[1] = f2bf(a0.y);
        af[2] = f2bf(a0.z); af[3] = f2bf(a0.w);
        af[4] = f2bf(a1.x); af[5] = f2bf(a1.y);
        af[6] = f2bf(a1.z); af[7] = f2bf(a1.w);

        f32x4 d0 = {bias0, bias0, bias0, bias0};
        f32x4 d1 = {bias1, bias1, bias1, bias1};
        f32x4 d2 = {bias2, bias2, bias2, bias2};
        f32x4 d3 = {bias3, bias3, bias3, bias3};
        d0 = __builtin_amdgcn_mfma_f32_16x16x32_bf16(af, wf0, d0, 0, 0, 0);
        d1 = __builtin_amdgcn_mfma_f32_16x16x32_bf16(af, wf1, d1, 0, 0, 0);
        d2 = __builtin_amdgcn_mfma_f32_16x16x32_bf16(af, wf2, d2, 0, 0, 0);
        d3 = __builtin_amdgcn_mfma_f32_16x16x32_bf16(af, wf3, d3, 0, 0, 0);

        // D row 4g+reg holds radial of image row b0 + sigma(4g+reg) = b0+4*reg+g
        TAIL(d0[0], d1[0], d2[0], d3[0], V_0.x, V_0.y, V_0.z, F0a, U_0.x, U_0.y, U_0.z)
        TAIL(d0[1], d1[1], d2[1], d3[1], V_1.x, V_1.y, V_1.z, F0b, U_1.x, U_1.y, U_1.z)
        TAIL(d0[2], d1[2], d2[2], d3[2], V_2.x, V_2.y, V_2.z, F0c, U_2.x, U_2.y, U_2.z)
        TAIL(d0[3], d1[3], d2[3], d3[3], V_3.x, V_3.y, V_3.z, F0d, U_3.x, U_3.y, U_3.z)
    }
#undef TAIL
#undef STAGE

    // ---- in-wave reduce over the 4 lane-groups sharing f ----
    #define WRED(x) x += __shfl_xor(x, 16); x += __shfl_xor(x, 32);
    WRED(acc1)  WRED(acc2x) WRED(acc2y) WRED(acc2z)
    WRED(acc3x) WRED(acc3y) WRED(acc3z) WRED(acc4)
    WRED(acc5x) WRED(acc5y) WRED(acc5z)
    #undef WRED

    if (lane < 16) {
        red[wave][f][0]  = acc1;
        red[wave][f][1]  = acc2x;
        red[wave][f][2]  = acc2y;
        red[wave][f][3]  = acc2z;
        red[wave][f][4]  = acc3x;
        red[wave][f][5]  = acc3y;
        red[wave][f][6]  = acc3z;
        red[wave][f][7]  = acc4;
        red[wave][f][8]  = acc5x;
        red[wave][f][9]  = acc5y;
        red[wave][f][10] = acc5z;
    }
    __syncthreads();

    if (t < 176) {
        const int ff = t / 11;
        const int comp = t % 11;
        float s = red[0][ff][comp] + red[1][ff][comp]
                + red[2][ff][comp] + red[3][ff][comp];

        const size_t base16 = (size_t)ma * 16 + ff;
        const size_t base48 = base16 * 3;
        if (comp == 0)      out[base16] = s;
        else if (comp < 4)  out[32768  + base48 + (comp - 1)] = s;
        else if (comp < 7)  out[131072 + base48 + (comp - 4)] = s;
        else if (comp == 7) out[229376 + base16] = s;
        else                out[262144 + base48 + (comp - 8)] = s;
    }
}

extern "C" void kernel_launch(void* const* d_in, const int* in_sizes, int n_in,
                              void* d_out, int out_size, void* d_ws, size_t ws_size,
                              hipStream_t stream) {
    const float* image   = (const float*)d_in[0];
    const float* vectors = (const float*)d_in[1];
    const float* feat0   = (const float*)d_in[2];
    const float* feat1   = (const float*)d_in[3];
    const float* W00 = (const float*)d_in[4];
    const float* b00 = (const float*)d_in[5];
    const float* W01 = (const float*)d_in[6];
    const float* b01 = (const float*)d_in[7];
    const float* W10 = (const float*)d_in[8];
    const float* b10 = (const float*)d_in[9];
    const float* W11 = (const float*)d_in[10];
    const float* b11 = (const float*)d_in[11];
    float* out = (float*)d_out;

    conv_mfma_coop_kernel<<<4 * 512, 256, 0, stream>>>(
        image, vectors, feat0, feat1,
        W00, b00, W01, b01, W10, b10, W11, b11, out);
}

// Round 10
// 222.419 us; speedup vs baseline: 1.6261x; 1.2139x over previous
//
#include <hip/hip_runtime.h>
#include <hip/hip_bf16.h>

// Problem: B=4, N=512, RBF=32, F=16
// image   (B,N,N,32) f32   d_in[0]
// vectors (B,N,N,3)  f32   d_in[1]
// feat0   (B,N,16,1) f32   d_in[2]
// feat1   (B,N,16,3) f32   d_in[3]
// W00,b00,W01,b01,W10,b10,W11,b11  d_in[4..11]
// out: out1(B,N,16,1) | out2(B,N,16,3) | out3(B,N,16,3) | out4(B,N,16,1) | out5(B,N,16,3)
//
// Round 10: image-ONLY LDS double-buffer (2KB/tile/wave, 16KB total + 3KB red).
// r9 lesson: staging L2-hot feat0/feat1 cost 52KB LDS + VGPR 164 (unroll-hoisted
// addresses) -> occupancy 11%, net loss. Here: image (HBM-cold stream) staged
// via global_load_lds with XOR chunk swizzle (r9-verified); feat0/feat1/vectors
// (L2-resident) loaded direct as in r6. #pragma unroll 1 pins register
// pressure (r9's VGPR blowup was unroll-induced address liveness).
// Barrier-per-tile is the compiler-native drain mechanism (no inline asm).

typedef __attribute__((ext_vector_type(8))) short short8;
typedef __attribute__((ext_vector_type(4))) float f32x4;

#define EPS2 1e-14f

static __device__ __forceinline__ short f2bf(float x) {
    __hip_bfloat16 h = __float2bfloat16(x);
    return *reinterpret_cast<short*>(&h);
}

static __device__ __forceinline__ void gload16(const void* g, void* l) {
    __builtin_amdgcn_global_load_lds(
        (const __attribute__((address_space(1))) void*)g,
        (__attribute__((address_space(3))) void*)l,
        16, 0, 0);
}

__global__ __launch_bounds__(256, 4) void conv_mfma_imgstage_kernel(
    const float* __restrict__ image,
    const float* __restrict__ vectors,
    const float* __restrict__ feat0,
    const float* __restrict__ feat1,
    const float* __restrict__ W00, const float* __restrict__ b00,
    const float* __restrict__ W01, const float* __restrict__ b01,
    const float* __restrict__ W10, const float* __restrict__ b10,
    const float* __restrict__ W11, const float* __restrict__ b11,
    float* __restrict__ out)
{
    // per-wave image double buffer: [wave][buf] of 2048B (16 rows x 128B)
    __shared__ __align__(16) char smem[4 * 2 * 2048];
    __shared__ float red[4][16][12];     // [wave][f][comp(11 pad 12)]

    const int t    = threadIdx.x;
    const int wave = t >> 6;
    const int lane = t & 63;
    const int f    = lane & 15;          // B col / D col
    const int g    = lane >> 4;          // k-group (A/B), row-group (D)
    const int ma   = blockIdx.x;         // m*512 + a
    const int m    = ma >> 9;

    // ---- weight fragments (VGPR-resident, once per block) ----
    short8 wf0, wf1, wf2, wf3;
    float bias0, bias1, bias2, bias3;
    {
        #pragma unroll
        for (int j = 0; j < 8; ++j) {
            const int k = g * 8 + j;
            wf0[j] = f2bf(W00[k * 16 + f]);
            wf1[j] = f2bf(W01[k * 16 + f]);
            wf2[j] = f2bf(W10[k * 16 + f]);
            wf3[j] = f2bf(W11[k * 16 + f]);
        }
        bias0 = b00[f]; bias1 = b01[f]; bias2 = b10[f]; bias3 = b11[f];
    }

    const float* imgbase = image   + (size_t)ma * (512 * 32);
    const float* vecbase = vectors + (size_t)ma * (512 * 3);
    const float* f0base  = feat0   + (size_t)m  * (512 * 16);
    const float* f1base  = feat1   + (size_t)m  * (512 * 16 * 3);

    float acc1 = 0.f, acc4 = 0.f;
    float acc2x = 0.f, acc2y = 0.f, acc2z = 0.f;
    float acc3x = 0.f, acc3y = 0.f, acc3z = 0.f;
    float acc5x = 0.f, acc5y = 0.f, acc5z = 0.f;

    const int bbase = wave * 128;        // wave's b range: [bbase, bbase+128)
    char* wbase = smem + wave * 4096;

    // staging source offset: LDS slot (r,s)=lane -> global row r, chunk s^(r&7)
    // (second gload covers rows 8-15; r&7 identical, so offset is +1024)
    const int r0 = lane >> 3, s0 = lane & 7;
    const int isrc0 = r0 * 128 + ((s0 ^ (r0 & 7)) << 4);
    // A-frag read offsets (loop-invariant): row f, global chunk j at slot j^(f&7)
    const int a0_off = f * 128 + (((2 * g)     ^ (f & 7)) << 4);
    const int a1_off = f * 128 + (((2 * g + 1) ^ (f & 7)) << 4);

#define STAGE(TT, BUF) { \
    const char* imgT_ = (const char*)(imgbase + (size_t)(bbase + (TT) * 16) * 32); \
    char* db_ = wbase + (BUF) * 2048; \
    gload16(imgT_ + isrc0,        db_); \
    gload16(imgT_ + isrc0 + 1024, db_ + 1024); \
}

#define TAIL(R00, R01, R10, R11, VX, VY, VZ, F0V, U0, U1, U2) { \
    const float vx_ = (VX), vy_ = (VY), vz_ = (VZ); \
    const float n2_ = vx_ * vx_ + vy_ * vy_ + vz_ * vz_; \
    const bool keep_ = n2_ >= EPS2; \
    const float r00_ = (R00); \
    const float r01_ = keep_ ? (R01) : 0.f; \
    const float r10_ = (R10); \
    const float r11_ = keep_ ? (R11) : 0.f; \
    const float f0v_ = (F0V); \
    const float u0_ = (U0), u1_ = (U1), u2_ = (U2); \
    acc1 = fmaf(r00_, f0v_, acc1); \
    const float t01_ = r01_ * f0v_; \
    acc2x = fmaf(t01_, vx_, acc2x); \
    acc2y = fmaf(t01_, vy_, acc2y); \
    acc2z = fmaf(t01_, vz_, acc2z); \
    acc3x = fmaf(r10_, u0_, acc3x); \
    acc3y = fmaf(r10_, u1_, acc3y); \
    acc3z = fmaf(r10_, u2_, acc3z); \
    const float dd_ = fmaf(vx_, u0_, fmaf(vy_, u1_, vz_ * u2_)); \
    acc4 = fmaf(r11_, dd_, acc4); \
    acc5x = fmaf(r11_, vy_ * u2_ - vz_ * u1_, acc5x); \
    acc5y = fmaf(r11_, vz_ * u0_ - vx_ * u2_, acc5y); \
    acc5z = fmaf(r11_, vx_ * u1_ - vy_ * u0_, acc5z); \
}

    // prologue: stage tile 0 into buf 0
    STAGE(0, 0)

    #pragma unroll 1
    for (int tt = 0; tt < 8; ++tt) {
        __syncthreads();                 // drains stage(tt) (compiler vmcnt)

        if (tt < 7) { STAGE(tt + 1, (tt + 1) & 1) }   // in flight under compute

        // ---- A fragment from LDS (swizzled, conflict-benign) ----
        const char* cb = wbase + (tt & 1) * 2048;
        const float4 a0 = *(const float4*)(cb + a0_off);
        const float4 a1 = *(const float4*)(cb + a1_off);

        // ---- L2-hot direct loads: lane owns b = b0 + 4*g + reg ----
        const int bb = bbase + tt * 16 + 4 * g;
        const float* vp = vecbase + bb * 3;          // 48B-aligned
        const float4 V0 = *(const float4*)(vp);
        const float4 V1 = *(const float4*)(vp + 4);
        const float4 V2 = *(const float4*)(vp + 8);
        const float* f0p = f0base + bb * 16 + f;
        const float F0a = f0p[0], F0b = f0p[16], F0c = f0p[32], F0d = f0p[48];
        const float* f1p = f1base + (size_t)(bb * 16 + f) * 3;
        const float3 U_0 = *(const float3*)(f1p);
        const float3 U_1 = *(const float3*)(f1p + 48);
        const float3 U_2 = *(const float3*)(f1p + 96);
        const float3 U_3 = *(const float3*)(f1p + 144);

        // ---- compute ----
        short8 af;
        af[0] = f2bf(a0.x); af[1] = f2bf(a0.y);
        af[2] = f2bf(a0.z); af[3] = f2bf(a0.w);
        af[4] = f2bf(a1.x); af[5] = f2bf(a1.y);
        af[6] = f2bf(a1.z); af[7] = f2bf(a1.w);

        f32x4 d0 = {bias0, bias0, bias0, bias0};
        f32x4 d1 = {bias1, bias1, bias1, bias1};
        f32x4 d2 = {bias2, bias2, bias2, bias2};
        f32x4 d3 = {bias3, bias3, bias3, bias3};
        d0 = __builtin_amdgcn_mfma_f32_16x16x32_bf16(af, wf0, d0, 0, 0, 0);
        d1 = __builtin_amdgcn_mfma_f32_16x16x32_bf16(af, wf1, d1, 0, 0, 0);
        d2 = __builtin_amdgcn_mfma_f32_16x16x32_bf16(af, wf2, d2, 0, 0, 0);
        d3 = __builtin_amdgcn_mfma_f32_16x16x32_bf16(af, wf3, d3, 0, 0, 0);

        TAIL(d0[0], d1[0], d2[0], d3[0], V0.x, V0.y, V0.z, F0a, U_0.x, U_0.y, U_0.z)
        TAIL(d0[1], d1[1], d2[1], d3[1], V0.w, V1.x, V1.y, F0b, U_1.x, U_1.y, U_1.z)
        TAIL(d0[2], d1[2], d2[2], d3[2], V1.z, V1.w, V2.x, F0c, U_2.x, U_2.y, U_2.z)
        TAIL(d0[3], d1[3], d2[3], d3[3], V2.y, V2.z, V2.w, F0d, U_3.x, U_3.y, U_3.z)
    }
#undef TAIL
#undef STAGE

    // ---- in-wave reduce over the 4 lane-groups sharing f ----
    #define WRED(x) x += __shfl_xor(x, 16); x += __shfl_xor(x, 32);
    WRED(acc1)  WRED(acc2x) WRED(acc2y) WRED(acc2z)
    WRED(acc3x) WRED(acc3y) WRED(acc3z) WRED(acc4)
    WRED(acc5x) WRED(acc5y) WRED(acc5z)
    #undef WRED

    if (lane < 16) {
        red[wave][f][0]  = acc1;
        red[wave][f][1]  = acc2x;
        red[wave][f][2]  = acc2y;
        red[wave][f][3]  = acc2z;
        red[wave][f][4]  = acc3x;
        red[wave][f][5]  = acc3y;
        red[wave][f][6]  = acc3z;
        red[wave][f][7]  = acc4;
        red[wave][f][8]  = acc5x;
        red[wave][f][9]  = acc5y;
        red[wave][f][10] = acc5z;
    }
    __syncthreads();

    if (t < 176) {
        const int ff = t / 11;
        const int comp = t % 11;
        float s = red[0][ff][comp] + red[1][ff][comp]
                + red[2][ff][comp] + red[3][ff][comp];

        const size_t base16 = (size_t)ma * 16 + ff;
        const size_t base48 = base16 * 3;
        if (comp == 0)      out[base16] = s;
        else if (comp < 4)  out[32768  + base48 + (comp - 1)] = s;
        else if (comp < 7)  out[131072 + base48 + (comp - 4)] = s;
        else if (comp == 7) out[229376 + base16] = s;
        else                out[262144 + base48 + (comp - 8)] = s;
    }
}

extern "C" void kernel_launch(void* const* d_in, const int* in_sizes, int n_in,
                              void* d_out, int out_size, void* d_ws, size_t ws_size,
                              hipStream_t stream) {
    const float* image   = (const float*)d_in[0];
    const float* vectors = (const float*)d_in[1];
    const float* feat0   = (const float*)d_in[2];
    const float* feat1   = (const float*)d_in[3];
    const float* W00 = (const float*)d_in[4];
    const float* b00 = (const float*)d_in[5];
    const float* W01 = (const float*)d_in[6];
    const float* b01 = (const float*)d_in[7];
    const float* W10 = (const float*)d_in[8];
    const float* b10 = (const float*)d_in[9];
    const float* W11 = (const float*)d_in[10];
    const float* b11 = (const float*)d_in[11];
    float* out = (float*)d_out;

    conv_mfma_imgstage_kernel<<<4 * 512, 256, 0, stream>>>(
        image, vectors, feat0, feat1,
        W00, b00, W01, b01, W10, b10, W11, b11, out);
}